// Round 2
// baseline (418.102 us; speedup 1.0000x reference)
//
#include <hip/hip_runtime.h>
#include <hip/hip_bf16.h>

typedef __bf16 bf16;
typedef __attribute__((ext_vector_type(8))) __bf16 bf16x8;
typedef __attribute__((ext_vector_type(4))) float f32x4;

static_assert(sizeof(bf16x8) == 16, "bf16x8 must be 16B");

#define S_LEN 2048
#define BATCH_N 2
#define DM 1024
#define NHEAD 16
#define HDIM 64

// Load 8 consecutive elements starting at elem_off, as bf16x8.
// F32=true: source is float32, convert (inputs are f32 per the reference).
template <bool F32>
__device__ __forceinline__ bf16x8 load8(const void* __restrict__ base, size_t elem_off) {
    if constexpr (F32) {
        const float* p = (const float*)base + elem_off;
        const f32x4 a = *(const f32x4*)p;
        const f32x4 b = *(const f32x4*)(p + 4);
        bf16x8 r;
        r[0] = (bf16)a[0]; r[1] = (bf16)a[1]; r[2] = (bf16)a[2]; r[3] = (bf16)a[3];
        r[4] = (bf16)b[0]; r[5] = (bf16)b[1]; r[6] = (bf16)b[2]; r[7] = (bf16)b[3];
        return r;
    } else {
        return *(const bf16x8*)((const bf16*)base + elem_off);
    }
}

// ---------------------------------------------------------------------------
// 128x128 bf16 MFMA GEMM tile: C = A * W^T
// A: MxK row-major, W: NxK row-major (both K-contiguous => identical frag loads)
// 256 threads = 4 waves in 2x2; each wave computes 64x64 via 4x4 mfma 16x16x32.
// C/D layout (m89/m91): col = lane&15, row = (lane>>4)*4 + reg.
// A/B frag layout: elem[m or n = lane&15][k = (lane>>4)*8 + j], j=0..7.
// ---------------------------------------------------------------------------
template <bool AF32, bool BF32>
__device__ __forceinline__ void gemm_tile(const void* __restrict__ A,
                                          const void* __restrict__ W,
                                          int row0, int col0, int Kdim,
                                          f32x4 acc[4][4]) {
    __shared__ bf16 As[128 * 32];
    __shared__ bf16 Bs[128 * 32];
    const int tid  = threadIdx.x;
    const int lane = tid & 63;
    const int wave = tid >> 6;
    const int wr = wave >> 1, wc = wave & 1;
    const int qr = lane & 15, quad = lane >> 4;

    const int sr = tid >> 2;        // staging row 0..63
    const int sc = (tid & 3) * 8;   // staging col 0/8/16/24

    const f32x4 fzero = {0.f, 0.f, 0.f, 0.f};
    #pragma unroll
    for (int mi = 0; mi < 4; ++mi)
        #pragma unroll
        for (int ni = 0; ni < 4; ++ni)
            acc[mi][ni] = fzero;

    for (int k0 = 0; k0 < Kdim; k0 += 32) {
        // global -> regs (converted to bf16)
        bf16x8 a0 = load8<AF32>(A, (size_t)(row0 + sr) * Kdim + k0 + sc);
        bf16x8 a1 = load8<AF32>(A, (size_t)(row0 + 64 + sr) * Kdim + k0 + sc);
        bf16x8 b0 = load8<BF32>(W, (size_t)(col0 + sr) * Kdim + k0 + sc);
        bf16x8 b1 = load8<BF32>(W, (size_t)(col0 + 64 + sr) * Kdim + k0 + sc);
        __syncthreads();   // protect previous iteration's LDS reads
        *(bf16x8*)(As + sr * 32 + sc)        = a0;
        *(bf16x8*)(As + (64 + sr) * 32 + sc) = a1;
        *(bf16x8*)(Bs + sr * 32 + sc)        = b0;
        *(bf16x8*)(Bs + (64 + sr) * 32 + sc) = b1;
        __syncthreads();

        bf16x8 af[4], bfr[4];
        #pragma unroll
        for (int mi = 0; mi < 4; ++mi)
            af[mi] = *(const bf16x8*)(As + (wr * 64 + mi * 16 + qr) * 32 + quad * 8);
        #pragma unroll
        for (int ni = 0; ni < 4; ++ni)
            bfr[ni] = *(const bf16x8*)(Bs + (wc * 64 + ni * 16 + qr) * 32 + quad * 8);
        #pragma unroll
        for (int mi = 0; mi < 4; ++mi)
            #pragma unroll
            for (int ni = 0; ni < 4; ++ni)
                acc[mi][ni] = __builtin_amdgcn_mfma_f32_16x16x32_bf16(
                    af[mi], bfr[ni], acc[mi][ni], 0, 0, 0);
    }
}

// ---------------------------------------------------------------------------
// QKV projection: X(4096x1024 f32) @ {Wq,Wk,Wv}^T + bias; scatter to bf16
//   Q  [b][h][s][dh]   (pre-scaled by 1/sqrt(Dh) = 0.125)
//   K  [b][h][s][dh]
//   Vt [b][h][dh][s]   (transposed so PV b-frags read contiguous s)
// ---------------------------------------------------------------------------
__global__ __launch_bounds__(256)
void qkv_kernel(const float* __restrict__ X,
                const float* __restrict__ Wq, const float* __restrict__ bq,
                const float* __restrict__ Wk, const float* __restrict__ bk,
                const float* __restrict__ Wv, const float* __restrict__ bv,
                bf16* __restrict__ Q, bf16* __restrict__ Kt, bf16* __restrict__ Vt) {
    const int mat  = blockIdx.z;
    const float* W    = (mat == 0) ? Wq : (mat == 1) ? Wk : Wv;
    const float* bias = (mat == 0) ? bq : (mat == 1) ? bk : bv;
    const int col0 = blockIdx.x * 128;
    const int row0 = blockIdx.y * 128;

    f32x4 acc[4][4];
    gemm_tile<true, true>(X, W, row0, col0, DM, acc);

    const int lane = threadIdx.x & 63;
    const int wave = threadIdx.x >> 6;
    const int wr = wave >> 1, wc = wave & 1;
    const int qr = lane & 15, quad = lane >> 4;

    #pragma unroll
    for (int ni = 0; ni < 4; ++ni) {
        const int n  = col0 + wc * 64 + ni * 16 + qr;
        const float bn = bias[n];
        const int h = n >> 6, dh = n & 63;
        #pragma unroll
        for (int mi = 0; mi < 4; ++mi) {
            #pragma unroll
            for (int r = 0; r < 4; ++r) {
                const int i = row0 + wr * 64 + mi * 16 + quad * 4 + r;
                const int s = i >> 1, b = i & 1;          // i = s*BATCH + b
                const float v = acc[mi][ni][r] + bn;
                if (mat == 0) {
                    Q[((size_t)(b * NHEAD + h) * S_LEN + s) * HDIM + dh] = (bf16)(v * 0.125f);
                } else if (mat == 1) {
                    Kt[((size_t)(b * NHEAD + h) * S_LEN + s) * HDIM + dh] = (bf16)v;
                } else {
                    Vt[((size_t)(b * NHEAD + h) * HDIM + dh) * S_LEN + s] = (bf16)v;
                }
            }
        }
    }
}

// ---------------------------------------------------------------------------
// Causal flash attention. Block = 64 query rows (4 waves x 16), key tiles of 32.
// ctx written as [s][b][h*64+dh] (row-major 4096x1024 bf16) for the out-proj.
// ---------------------------------------------------------------------------
__global__ __launch_bounds__(256)
void attn_kernel(const bf16* __restrict__ Q, const bf16* __restrict__ K,
                 const bf16* __restrict__ Vt, bf16* __restrict__ ctx) {
    __shared__ bf16 Pbuf[4][16 * 32];   // per-wave P tile (16 q x 32 k)
    const int lane = threadIdx.x & 63;
    const int wave = threadIdx.x >> 6;
    const int qr = lane & 15, quad = lane >> 4;
    const int bh = blockIdx.y;               // b*NHEAD + h
    const int b = bh >> 4, h = bh & 15;
    const int q_blk = blockIdx.x * 64;
    const int q0 = q_blk + wave * 16;        // this wave's 16 query rows

    const bf16* Qb = Q  + (size_t)bh * S_LEN * HDIM;
    const bf16* Kb = K  + (size_t)bh * S_LEN * HDIM;
    const bf16* Vb = Vt + (size_t)bh * HDIM * S_LEN;

    // Q a-frags held in regs for the whole KV loop (Q pre-scaled by 0.125)
    const bf16x8 q_lo = *(const bf16x8*)(Qb + (size_t)(q0 + qr) * HDIM + quad * 8);
    const bf16x8 q_hi = *(const bf16x8*)(Qb + (size_t)(q0 + qr) * HDIM + quad * 8 + 32);

    float m_run[4] = {-1e30f, -1e30f, -1e30f, -1e30f};
    float l_run[4] = {0.f, 0.f, 0.f, 0.f};
    const f32x4 fzero = {0.f, 0.f, 0.f, 0.f};
    f32x4 o[4];
    #pragma unroll
    for (int ni = 0; ni < 4; ++ni) o[ni] = fzero;

    const int kend = q_blk + 64;   // block-uniform => __syncthreads is safe
    for (int k0 = 0; k0 < kend; k0 += 32) {
        // K b-frags: lane reads K[t = k0(+16) + (lane&15)][dh = quad*8 .. +8]
        const bf16x8 kA_lo = *(const bf16x8*)(Kb + (size_t)(k0 + qr) * HDIM + quad * 8);
        const bf16x8 kA_hi = *(const bf16x8*)(Kb + (size_t)(k0 + qr) * HDIM + quad * 8 + 32);
        const bf16x8 kB_lo = *(const bf16x8*)(Kb + (size_t)(k0 + 16 + qr) * HDIM + quad * 8);
        const bf16x8 kB_hi = *(const bf16x8*)(Kb + (size_t)(k0 + 16 + qr) * HDIM + quad * 8 + 32);

        f32x4 S0 = __builtin_amdgcn_mfma_f32_16x16x32_bf16(q_lo, kA_lo, fzero, 0, 0, 0);
        S0 = __builtin_amdgcn_mfma_f32_16x16x32_bf16(q_hi, kA_hi, S0, 0, 0, 0);
        f32x4 S1 = __builtin_amdgcn_mfma_f32_16x16x32_bf16(q_lo, kB_lo, fzero, 0, 0, 0);
        S1 = __builtin_amdgcn_mfma_f32_16x16x32_bf16(q_hi, kB_hi, S1, 0, 0, 0);

        float alpha[4];
        #pragma unroll
        for (int r = 0; r < 4; ++r) {
            const int qrow = q0 + quad * 4 + r;
            // causal: key t valid iff t <= qrow
            float s0 = (k0 + qr      <= qrow) ? S0[r] : -1e30f;
            float s1 = (k0 + 16 + qr <= qrow) ? S1[r] : -1e30f;
            float mx = fmaxf(s0, s1);
            mx = fmaxf(mx, __shfl_xor(mx, 1));
            mx = fmaxf(mx, __shfl_xor(mx, 2));
            mx = fmaxf(mx, __shfl_xor(mx, 4));
            mx = fmaxf(mx, __shfl_xor(mx, 8));
            const float mnew = fmaxf(m_run[r], mx);
            alpha[r] = __expf(m_run[r] - mnew);
            m_run[r] = mnew;
            const float p0 = __expf(s0 - mnew);
            const float p1 = __expf(s1 - mnew);
            // P (C-layout) -> LDS as [q][k] row-major 16x32
            Pbuf[wave][(quad * 4 + r) * 32 + qr]      = (bf16)p0;
            Pbuf[wave][(quad * 4 + r) * 32 + 16 + qr] = (bf16)p1;
            float rs = p0 + p1;
            rs += __shfl_xor(rs, 1);
            rs += __shfl_xor(rs, 2);
            rs += __shfl_xor(rs, 4);
            rs += __shfl_xor(rs, 8);
            l_run[r] = l_run[r] * alpha[r] + rs;
        }
        #pragma unroll
        for (int ni = 0; ni < 4; ++ni)
            #pragma unroll
            for (int r = 0; r < 4; ++r)
                o[ni][r] *= alpha[r];

        __syncthreads();   // make P visible before a-frag read
        // P a-frag: lane reads P[m = lane&15][k = quad*8 .. +8]
        const bf16x8 pf = *(const bf16x8*)(&Pbuf[wave][qr * 32 + quad * 8]);
        #pragma unroll
        for (int ni = 0; ni < 4; ++ni) {
            // V b-frag: lane reads V[k = k0 + quad*8 + j][dh = ni*16 + (lane&15)]
            // via Vt[dh][s] (contiguous in s)
            const bf16x8 vf = *(const bf16x8*)(Vb + (size_t)(ni * 16 + qr) * S_LEN + k0 + quad * 8);
            o[ni] = __builtin_amdgcn_mfma_f32_16x16x32_bf16(pf, vf, o[ni], 0, 0, 0);
        }
        __syncthreads();
    }

    #pragma unroll
    for (int ni = 0; ni < 4; ++ni) {
        const int dh = ni * 16 + qr;
        #pragma unroll
        for (int r = 0; r < 4; ++r) {
            const int srow = q0 + quad * 4 + r;
            const float val = o[ni][r] / l_run[r];
            ctx[((size_t)(srow * BATCH_N + b) * NHEAD + h) * HDIM + dh] = (bf16)val;
        }
    }
}

// ---------------------------------------------------------------------------
// Output projection: ctx(4096x1024 bf16) @ out_w^T + out_b -> d_out f32 [s][b][d]
// ---------------------------------------------------------------------------
__global__ __launch_bounds__(256)
void proj_kernel(const bf16* __restrict__ X, const float* __restrict__ W,
                 const float* __restrict__ bias, float* __restrict__ out) {
    const int col0 = blockIdx.x * 128;
    const int row0 = blockIdx.y * 128;
    f32x4 acc[4][4];
    gemm_tile<false, true>(X, W, row0, col0, DM, acc);

    const int lane = threadIdx.x & 63;
    const int wave = threadIdx.x >> 6;
    const int wr = wave >> 1, wc = wave & 1;
    const int qr = lane & 15, quad = lane >> 4;

    #pragma unroll
    for (int ni = 0; ni < 4; ++ni) {
        const int n = col0 + wc * 64 + ni * 16 + qr;
        const float bn = bias[n];
        #pragma unroll
        for (int mi = 0; mi < 4; ++mi) {
            #pragma unroll
            for (int r = 0; r < 4; ++r) {
                const int i = row0 + wr * 64 + mi * 16 + quad * 4 + r;
                out[(size_t)i * DM + n] = acc[mi][ni][r] + bn;
            }
        }
    }
}

extern "C" void kernel_launch(void* const* d_in, const int* in_sizes, int n_in,
                              void* d_out, int out_size, void* d_ws, size_t ws_size,
                              hipStream_t stream) {
    (void)in_sizes; (void)n_in; (void)out_size; (void)ws_size;
    const float* query = (const float*)d_in[0];
    const float* q_w   = (const float*)d_in[1];
    const float* q_b   = (const float*)d_in[2];
    const float* k_w   = (const float*)d_in[3];
    const float* k_b   = (const float*)d_in[4];
    const float* v_w   = (const float*)d_in[5];
    const float* v_b   = (const float*)d_in[6];
    const float* out_w = (const float*)d_in[7];
    const float* out_b = (const float*)d_in[8];
    // d_in[9] = attn_mask: deterministic causal -> recomputed in-kernel, unused.

    char* ws = (char*)d_ws;
    bf16* Qb  = (bf16*)(ws);                       // 8 MB  [b][h][s][dh]
    bf16* Kb  = (bf16*)(ws + ((size_t)8  << 20));  // 8 MB  [b][h][s][dh]
    bf16* Vt  = (bf16*)(ws + ((size_t)16 << 20));  // 8 MB  [b][h][dh][s]
    bf16* ctx = (bf16*)(ws + ((size_t)24 << 20));  // 8 MB  [s*B+b][1024]
    float* out = (float*)d_out;

    dim3 blk(256);
    qkv_kernel<<<dim3(DM / 128, (S_LEN * BATCH_N) / 128, 3), blk, 0, stream>>>(
        query, q_w, q_b, k_w, k_b, v_w, v_b, Qb, Kb, Vt);
    attn_kernel<<<dim3(S_LEN / 64, BATCH_N * NHEAD), blk, 0, stream>>>(Qb, Kb, Vt, ctx);
    proj_kernel<<<dim3(DM / 128, (S_LEN * BATCH_N) / 128), blk, 0, stream>>>(
        ctx, out_w, out_b, out);
}

// Round 3
// 300.807 us; speedup vs baseline: 1.3899x; 1.3899x over previous
//
#include <hip/hip_runtime.h>
#include <hip/hip_bf16.h>

typedef __bf16 bf16;
typedef __attribute__((ext_vector_type(4))) __bf16 bf16x4;
typedef __attribute__((ext_vector_type(8))) __bf16 bf16x8;
typedef __attribute__((ext_vector_type(4))) float f32x4;

static_assert(sizeof(bf16x8) == 16, "bf16x8 must be 16B");

#define S_LEN 2048
#define BATCH_N 2
#define DM 1024
#define NHEAD 16
#define HDIM 64

// ---------------------------------------------------------------------------
// f32 -> bf16 element-wise convert, 8 elems/thread. n must be divisible by 2048.
// ---------------------------------------------------------------------------
__global__ __launch_bounds__(256)
void cvt_f32_bf16(const float* __restrict__ src, bf16* __restrict__ dst) {
    const size_t i = ((size_t)blockIdx.x * 256 + threadIdx.x) * 8;
    const f32x4 a = *(const f32x4*)(src + i);
    const f32x4 b = *(const f32x4*)(src + i + 4);
    bf16x8 r;
    r[0] = (bf16)a[0]; r[1] = (bf16)a[1]; r[2] = (bf16)a[2]; r[3] = (bf16)a[3];
    r[4] = (bf16)b[0]; r[5] = (bf16)b[1]; r[6] = (bf16)b[2]; r[7] = (bf16)b[3];
    *(bf16x8*)(dst + i) = r;
}

// ---------------------------------------------------------------------------
// 128x128 bf16 MFMA GEMM tile: C = A * W^T  (both A and W K-contiguous bf16)
// 256 threads = 4 waves in 2x2; each wave 64x64 via 4x4 mfma 16x16x32.
// C/D layout: col = lane&15, row = (lane>>4)*4 + reg.
// A/B frag:   elem[m or n = lane&15][k = (lane>>4)*8 + j].
// ---------------------------------------------------------------------------
__device__ __forceinline__ void gemm_tile(const bf16* __restrict__ A,
                                          const bf16* __restrict__ W,
                                          int row0, int col0, int Kdim,
                                          f32x4 acc[4][4]) {
    __shared__ bf16 As[128 * 32];
    __shared__ bf16 Bs[128 * 32];
    const int tid  = threadIdx.x;
    const int lane = tid & 63;
    const int wave = tid >> 6;
    const int wr = wave >> 1, wc = wave & 1;
    const int qr = lane & 15, quad = lane >> 4;

    const int sr = tid >> 2;        // staging row 0..63
    const int sc = (tid & 3) * 8;   // staging col 0/8/16/24

    const f32x4 fzero = {0.f, 0.f, 0.f, 0.f};
    #pragma unroll
    for (int mi = 0; mi < 4; ++mi)
        #pragma unroll
        for (int ni = 0; ni < 4; ++ni)
            acc[mi][ni] = fzero;

    for (int k0 = 0; k0 < Kdim; k0 += 32) {
        bf16x8 a0 = *(const bf16x8*)(A + (size_t)(row0 + sr) * Kdim + k0 + sc);
        bf16x8 a1 = *(const bf16x8*)(A + (size_t)(row0 + 64 + sr) * Kdim + k0 + sc);
        bf16x8 b0 = *(const bf16x8*)(W + (size_t)(col0 + sr) * Kdim + k0 + sc);
        bf16x8 b1 = *(const bf16x8*)(W + (size_t)(col0 + 64 + sr) * Kdim + k0 + sc);
        __syncthreads();   // protect previous iteration's LDS reads
        *(bf16x8*)(As + sr * 32 + sc)        = a0;
        *(bf16x8*)(As + (64 + sr) * 32 + sc) = a1;
        *(bf16x8*)(Bs + sr * 32 + sc)        = b0;
        *(bf16x8*)(Bs + (64 + sr) * 32 + sc) = b1;
        __syncthreads();

        bf16x8 af[4], bfr[4];
        #pragma unroll
        for (int mi = 0; mi < 4; ++mi)
            af[mi] = *(const bf16x8*)(As + (wr * 64 + mi * 16 + qr) * 32 + quad * 8);
        #pragma unroll
        for (int ni = 0; ni < 4; ++ni)
            bfr[ni] = *(const bf16x8*)(Bs + (wc * 64 + ni * 16 + qr) * 32 + quad * 8);
        #pragma unroll
        for (int mi = 0; mi < 4; ++mi)
            #pragma unroll
            for (int ni = 0; ni < 4; ++ni)
                acc[mi][ni] = __builtin_amdgcn_mfma_f32_16x16x32_bf16(
                    af[mi], bfr[ni], acc[mi][ni], 0, 0, 0);
    }
}

// ---------------------------------------------------------------------------
// QKV projection: Xb(4096x1024 bf16) @ {Wq,Wk,Wv}^T + bias; scatter to bf16
//   Q  [b][h][s][dh]   (pre-scaled by 1/sqrt(Dh) = 0.125)
//   K  [b][h][s][dh]
//   Vt [b][h][dh][s]
// ---------------------------------------------------------------------------
__global__ __launch_bounds__(256)
void qkv_kernel(const bf16* __restrict__ X,
                const bf16* __restrict__ Wq, const float* __restrict__ bq,
                const bf16* __restrict__ Wk, const float* __restrict__ bk,
                const bf16* __restrict__ Wv, const float* __restrict__ bv,
                bf16* __restrict__ Q, bf16* __restrict__ Kt, bf16* __restrict__ Vt) {
    const int mat  = blockIdx.z;
    const bf16*  W    = (mat == 0) ? Wq : (mat == 1) ? Wk : Wv;
    const float* bias = (mat == 0) ? bq : (mat == 1) ? bk : bv;
    const int col0 = blockIdx.x * 128;
    const int row0 = blockIdx.y * 128;

    f32x4 acc[4][4];
    gemm_tile(X, W, row0, col0, DM, acc);

    const int lane = threadIdx.x & 63;
    const int wave = threadIdx.x >> 6;
    const int wr = wave >> 1, wc = wave & 1;
    const int qr = lane & 15, quad = lane >> 4;

    #pragma unroll
    for (int ni = 0; ni < 4; ++ni) {
        const int n  = col0 + wc * 64 + ni * 16 + qr;
        const float bn = bias[n];
        const int h = n >> 6, dh = n & 63;
        #pragma unroll
        for (int mi = 0; mi < 4; ++mi) {
            #pragma unroll
            for (int r = 0; r < 4; ++r) {
                const int i = row0 + wr * 64 + mi * 16 + quad * 4 + r;
                const int s = i >> 1, b = i & 1;          // i = s*BATCH + b
                const float v = acc[mi][ni][r] + bn;
                if (mat == 0) {
                    Q[((size_t)(b * NHEAD + h) * S_LEN + s) * HDIM + dh] = (bf16)(v * 0.125f);
                } else if (mat == 1) {
                    Kt[((size_t)(b * NHEAD + h) * S_LEN + s) * HDIM + dh] = (bf16)v;
                } else {
                    Vt[((size_t)(b * NHEAD + h) * HDIM + dh) * S_LEN + s] = (bf16)v;
                }
            }
        }
    }
}

// ---------------------------------------------------------------------------
// Causal flash attention, transposed-score formulation.
//   S^T = K·Q^T  (C layout: col = q, row = k)  -> softmax state per-lane scalar
//   O^T = V^T·P^T (A-frag = Vt rows, B-frag = P^T via wave-local LDS transform)
// Block = 128 q rows: 4 waves x 2 q-tiles of 16. No __syncthreads anywhere.
// Per-wave loop bound k0 <= q0 (causal). Reversed dispatch: big blocks first.
// ---------------------------------------------------------------------------
#define PLD 40   // P row stride (bf16): 32 + 8 pad -> conflict-free b64/b128

__global__ __launch_bounds__(256, 2)
void attn_kernel(const bf16* __restrict__ Q, const bf16* __restrict__ K,
                 const bf16* __restrict__ Vt, bf16* __restrict__ ctx) {
    __shared__ bf16 Pbuf[4][2][16 * PLD];
    const int lane = threadIdx.x & 63;
    const int wave = threadIdx.x >> 6;
    const int qr = lane & 15, quad = lane >> 4;
    const int bh = blockIdx.y;               // b*NHEAD + h
    const int b = bh >> 4, h = bh & 15;
    const int q_blk = (gridDim.x - 1 - blockIdx.x) * 128;
    const int q0 = q_blk + wave * 32;        // this wave's 32 query rows

    const bf16* Qb = Q  + (size_t)bh * S_LEN * HDIM;
    const bf16* Kb = K  + (size_t)bh * S_LEN * HDIM;
    const bf16* Vb = Vt + (size_t)bh * HDIM * S_LEN;

    // Q b-frags for the two q-tiles (rows q0+qr and q0+16+qr), Q pre-scaled.
    const bf16x8 qa_lo = *(const bf16x8*)(Qb + (size_t)(q0 + qr) * HDIM + quad * 8);
    const bf16x8 qa_hi = *(const bf16x8*)(Qb + (size_t)(q0 + qr) * HDIM + quad * 8 + 32);
    const bf16x8 qb_lo = *(const bf16x8*)(Qb + (size_t)(q0 + 16 + qr) * HDIM + quad * 8);
    const bf16x8 qb_hi = *(const bf16x8*)(Qb + (size_t)(q0 + 16 + qr) * HDIM + quad * 8 + 32);

    float m0 = -1e30f, l0 = 0.f, m1 = -1e30f, l1 = 0.f;
    const f32x4 fzero = {0.f, 0.f, 0.f, 0.f};
    f32x4 o0[4], o1[4];
    #pragma unroll
    for (int ni = 0; ni < 4; ++ni) { o0[ni] = fzero; o1[ni] = fzero; }

    bf16* P0 = &Pbuf[wave][0][0];
    bf16* P1 = &Pbuf[wave][1][0];

    for (int k0 = 0; k0 <= q0; k0 += 32) {
        asm volatile("" ::: "memory");   // fence LDS motion across iterations
        // K a-frags: lane holds K rows k0+qr (half A) / k0+16+qr (half B)
        const bf16x8 kA_lo = *(const bf16x8*)(Kb + (size_t)(k0 + qr) * HDIM + quad * 8);
        const bf16x8 kA_hi = *(const bf16x8*)(Kb + (size_t)(k0 + qr) * HDIM + quad * 8 + 32);
        const bf16x8 kB_lo = *(const bf16x8*)(Kb + (size_t)(k0 + 16 + qr) * HDIM + quad * 8);
        const bf16x8 kB_hi = *(const bf16x8*)(Kb + (size_t)(k0 + 16 + qr) * HDIM + quad * 8 + 32);

        // S^T tiles: row = k (quad*4+r), col = q (qr)
        f32x4 sA0 = __builtin_amdgcn_mfma_f32_16x16x32_bf16(kA_lo, qa_lo, fzero, 0, 0, 0);
        sA0 = __builtin_amdgcn_mfma_f32_16x16x32_bf16(kA_hi, qa_hi, sA0, 0, 0, 0);
        f32x4 sB0 = __builtin_amdgcn_mfma_f32_16x16x32_bf16(kB_lo, qa_lo, fzero, 0, 0, 0);
        sB0 = __builtin_amdgcn_mfma_f32_16x16x32_bf16(kB_hi, qa_hi, sB0, 0, 0, 0);
        f32x4 sA1 = __builtin_amdgcn_mfma_f32_16x16x32_bf16(kA_lo, qb_lo, fzero, 0, 0, 0);
        sA1 = __builtin_amdgcn_mfma_f32_16x16x32_bf16(kA_hi, qb_hi, sA1, 0, 0, 0);
        f32x4 sB1 = __builtin_amdgcn_mfma_f32_16x16x32_bf16(kB_lo, qb_lo, fzero, 0, 0, 0);
        sB1 = __builtin_amdgcn_mfma_f32_16x16x32_bf16(kB_hi, qb_hi, sB1, 0, 0, 0);

        float alpha0, alpha1;
        // ---- tile 0 softmax (q = q0 + qr) ----
        {
            const int qrow = q0 + qr;
            float p[8];
            #pragma unroll
            for (int r = 0; r < 4; ++r) {
                p[r]     = (k0 + quad * 4 + r      <= qrow) ? sA0[r] : -1e30f;
                p[4 + r] = (k0 + 16 + quad * 4 + r <= qrow) ? sB0[r] : -1e30f;
            }
            float mx = p[0];
            #pragma unroll
            for (int j = 1; j < 8; ++j) mx = fmaxf(mx, p[j]);
            mx = fmaxf(mx, __shfl_xor(mx, 16));
            mx = fmaxf(mx, __shfl_xor(mx, 32));
            const float mnew = fmaxf(m0, mx);
            alpha0 = __expf(m0 - mnew);
            m0 = mnew;
            float rs = 0.f;
            #pragma unroll
            for (int j = 0; j < 8; ++j) { p[j] = __expf(p[j] - mnew); rs += p[j]; }
            rs += __shfl_xor(rs, 16);
            rs += __shfl_xor(rs, 32);
            l0 = l0 * alpha0 + rs;
            bf16x4 w0 = {(bf16)p[0], (bf16)p[1], (bf16)p[2], (bf16)p[3]};
            bf16x4 w1 = {(bf16)p[4], (bf16)p[5], (bf16)p[6], (bf16)p[7]};
            *(bf16x4*)(P0 + qr * PLD + quad * 4)      = w0;   // P[q][k=quad*4+r]
            *(bf16x4*)(P0 + qr * PLD + 16 + quad * 4) = w1;   // P[q][k=16+quad*4+r]
        }
        // ---- tile 1 softmax (q = q0 + 16 + qr) ----
        {
            const int qrow = q0 + 16 + qr;
            float p[8];
            #pragma unroll
            for (int r = 0; r < 4; ++r) {
                p[r]     = (k0 + quad * 4 + r      <= qrow) ? sA1[r] : -1e30f;
                p[4 + r] = (k0 + 16 + quad * 4 + r <= qrow) ? sB1[r] : -1e30f;
            }
            float mx = p[0];
            #pragma unroll
            for (int j = 1; j < 8; ++j) mx = fmaxf(mx, p[j]);
            mx = fmaxf(mx, __shfl_xor(mx, 16));
            mx = fmaxf(mx, __shfl_xor(mx, 32));
            const float mnew = fmaxf(m1, mx);
            alpha1 = __expf(m1 - mnew);
            m1 = mnew;
            float rs = 0.f;
            #pragma unroll
            for (int j = 0; j < 8; ++j) { p[j] = __expf(p[j] - mnew); rs += p[j]; }
            rs += __shfl_xor(rs, 16);
            rs += __shfl_xor(rs, 32);
            l1 = l1 * alpha1 + rs;
            bf16x4 w0 = {(bf16)p[0], (bf16)p[1], (bf16)p[2], (bf16)p[3]};
            bf16x4 w1 = {(bf16)p[4], (bf16)p[5], (bf16)p[6], (bf16)p[7]};
            *(bf16x4*)(P1 + qr * PLD + quad * 4)      = w0;
            *(bf16x4*)(P1 + qr * PLD + 16 + quad * 4) = w1;
        }

        // rescale O^T (alpha is per-lane scalar: col q = qr)
        #pragma unroll
        for (int ni = 0; ni < 4; ++ni) {
            #pragma unroll
            for (int r = 0; r < 4; ++r) { o0[ni][r] *= alpha0; o1[ni][r] *= alpha1; }
        }

        // wave-local LDS round-trip: drain P stores, then read P^T B-frags
        asm volatile("s_waitcnt lgkmcnt(0)" ::: "memory");
        const bf16x8 pf0 = *(const bf16x8*)(P0 + qr * PLD + quad * 8);
        const bf16x8 pf1 = *(const bf16x8*)(P1 + qr * PLD + quad * 8);

        #pragma unroll
        for (int ni = 0; ni < 4; ++ni) {
            // V^T a-frag: lane holds Vt[dh = ni*16+qr][k0 + quad*8 + j]
            const bf16x8 vf = *(const bf16x8*)(Vb + (size_t)(ni * 16 + qr) * S_LEN + k0 + quad * 8);
            o0[ni] = __builtin_amdgcn_mfma_f32_16x16x32_bf16(vf, pf0, o0[ni], 0, 0, 0);
            o1[ni] = __builtin_amdgcn_mfma_f32_16x16x32_bf16(vf, pf1, o1[ni], 0, 0, 0);
        }
    }

    // Epilogue: O^T lane holds (q = qr fixed, dh = ni*16 + quad*4 + r)
    const float inv0 = 1.f / l0, inv1 = 1.f / l1;
    #pragma unroll
    for (int ni = 0; ni < 4; ++ni) {
        bf16x4 c0, c1;
        #pragma unroll
        for (int r = 0; r < 4; ++r) {
            c0[r] = (bf16)(o0[ni][r] * inv0);
            c1[r] = (bf16)(o1[ni][r] * inv1);
        }
        const size_t dcol = h * 64 + ni * 16 + quad * 4;
        *(bf16x4*)(ctx + (size_t)((q0 + qr) * BATCH_N + b) * DM + dcol)      = c0;
        *(bf16x4*)(ctx + (size_t)((q0 + 16 + qr) * BATCH_N + b) * DM + dcol) = c1;
    }
}

// ---------------------------------------------------------------------------
// Output projection: ctx(4096x1024 bf16) @ out_w^T + out_b -> d_out f32 [s][b][d]
// ---------------------------------------------------------------------------
__global__ __launch_bounds__(256)
void proj_kernel(const bf16* __restrict__ X, const bf16* __restrict__ W,
                 const float* __restrict__ bias, float* __restrict__ out) {
    const int col0 = blockIdx.x * 128;
    const int row0 = blockIdx.y * 128;
    f32x4 acc[4][4];
    gemm_tile(X, W, row0, col0, DM, acc);

    const int lane = threadIdx.x & 63;
    const int wave = threadIdx.x >> 6;
    const int wr = wave >> 1, wc = wave & 1;
    const int qr = lane & 15, quad = lane >> 4;

    #pragma unroll
    for (int ni = 0; ni < 4; ++ni) {
        const int n = col0 + wc * 64 + ni * 16 + qr;
        const float bn = bias[n];
        #pragma unroll
        for (int mi = 0; mi < 4; ++mi) {
            #pragma unroll
            for (int r = 0; r < 4; ++r) {
                const int i = row0 + wr * 64 + mi * 16 + quad * 4 + r;
                out[(size_t)i * DM + n] = acc[mi][ni][r] + bn;
            }
        }
    }
}

extern "C" void kernel_launch(void* const* d_in, const int* in_sizes, int n_in,
                              void* d_out, int out_size, void* d_ws, size_t ws_size,
                              hipStream_t stream) {
    (void)in_sizes; (void)n_in; (void)out_size; (void)ws_size;
    const float* query = (const float*)d_in[0];
    const float* q_w   = (const float*)d_in[1];
    const float* q_b   = (const float*)d_in[2];
    const float* k_w   = (const float*)d_in[3];
    const float* k_b   = (const float*)d_in[4];
    const float* v_w   = (const float*)d_in[5];
    const float* v_b   = (const float*)d_in[6];
    const float* out_w = (const float*)d_in[7];
    const float* out_b = (const float*)d_in[8];
    // d_in[9] = attn_mask: deterministic causal -> recomputed in-kernel.

    char* ws = (char*)d_ws;
    bf16* Xb  = (bf16*)(ws);                        // 8 MB  [s*B+b][1024] bf16
    bf16* Wqb = (bf16*)(ws + ((size_t)8  << 20));   // 2 MB
    bf16* Wkb = (bf16*)(ws + ((size_t)10 << 20));   // 2 MB
    bf16* Wvb = (bf16*)(ws + ((size_t)12 << 20));   // 2 MB
    bf16* Wob = (bf16*)(ws + ((size_t)14 << 20));   // 2 MB
    bf16* Qb  = (bf16*)(ws + ((size_t)16 << 20));   // 8 MB  [b][h][s][dh]
    bf16* Kb  = (bf16*)(ws + ((size_t)24 << 20));   // 8 MB  [b][h][s][dh]
    bf16* Vt  = (bf16*)(ws + ((size_t)32 << 20));   // 8 MB  [b][h][dh][s]
    bf16* ctx = (bf16*)(ws + ((size_t)40 << 20));   // 8 MB  [s*B+b][1024]
    float* out = (float*)d_out;

    dim3 blk(256);
    // f32 -> bf16 preconversion (removes f32 staging + cvts from GEMM loops)
    cvt_f32_bf16<<<dim3((S_LEN * BATCH_N * DM) / 2048), blk, 0, stream>>>(query, Xb);
    cvt_f32_bf16<<<dim3((DM * DM) / 2048), blk, 0, stream>>>(q_w, Wqb);
    cvt_f32_bf16<<<dim3((DM * DM) / 2048), blk, 0, stream>>>(k_w, Wkb);
    cvt_f32_bf16<<<dim3((DM * DM) / 2048), blk, 0, stream>>>(v_w, Wvb);
    cvt_f32_bf16<<<dim3((DM * DM) / 2048), blk, 0, stream>>>(out_w, Wob);

    qkv_kernel<<<dim3(DM / 128, (S_LEN * BATCH_N) / 128, 3), blk, 0, stream>>>(
        Xb, Wqb, q_b, Wkb, k_b, Wvb, v_b, Qb, Kb, Vt);
    attn_kernel<<<dim3(S_LEN / 128, BATCH_N * NHEAD), blk, 0, stream>>>(Qb, Kb, Vt, ctx);
    proj_kernel<<<dim3(DM / 128, (S_LEN * BATCH_N) / 128), blk, 0, stream>>>(
        ctx, out_w ? Wob : Wob, out_b, out);
}